// Round 10
// baseline (3902.724 us; speedup 1.0000x reference)
//
#include <hip/hip_runtime.h>

#define B_ 256
#define T_ 512
#define I_ 512
#define H_ 1024
#define O_ 128
#define BT_ (B_*T_)

typedef short s16x8 __attribute__((ext_vector_type(8)));
typedef float f32x4 __attribute__((ext_vector_type(4)));

#define MFMA16(a,b,c) __builtin_amdgcn_mfma_f32_16x16x32_bf16(a, b, c, 0, 0, 0)

__device__ __forceinline__ short f2bf(float x){
  unsigned u = __float_as_uint(x);
  u = u + 0x7FFFu + ((u >> 16) & 1u);
  return (short)(u >> 16);
}
__device__ __forceinline__ float bf2f(short h){
  return __uint_as_float(((unsigned)(unsigned short)h) << 16);
}

// sc0-only 16B load: bypasses L1, served by the XCD-shared L2 (producer and
// consumer are guaranteed same-XCD by the role negotiation). Proven R5-R9.
__device__ __forceinline__ s16x8 cload16_l2(const short* p){
  s16x8 r;
  asm volatile("global_load_dwordx4 %0, %1, off sc0" : "=&v"(r) : "v"(p));
  return r;
}

__device__ __forceinline__ void stage16(const float* __restrict__ src, short* dst){
  float4 v0 = *(const float4*)(src + 0);
  float4 v1 = *(const float4*)(src + 4);
  float4 v2 = *(const float4*)(src + 8);
  float4 v3 = *(const float4*)(src + 12);
  s16x8 t0 = { f2bf(v0.x), f2bf(v0.y), f2bf(v0.z), f2bf(v0.w),
               f2bf(v1.x), f2bf(v1.y), f2bf(v1.z), f2bf(v1.w) };
  s16x8 t1 = { f2bf(v2.x), f2bf(v2.y), f2bf(v2.z), f2bf(v2.w),
               f2bf(v3.x), f2bf(v3.y), f2bf(v3.z), f2bf(v3.w) };
  *(s16x8*)(dst)     = t0;
  *(s16x8*)(dst + 8) = t1;
}

// ---------------- init: zero flags + role counters ----------------
__global__ void init_cnt(int* __restrict__ cnt){
  for (int i = threadIdx.x; i < (256 + 8) * 32; i += blockDim.x)
    __hip_atomic_store(cnt + i, 0, __ATOMIC_RELAXED, __HIP_MEMORY_SCOPE_AGENT);
}

// ---------------- phase 1: xw = x @ W_in^T + b_in  ->  hid ----------------
__global__ __launch_bounds__(256) void gemm_xw(const float* __restrict__ A,
                                               const float* __restrict__ Wn,
                                               const float* __restrict__ bias,
                                               float* __restrict__ out){
  __shared__ __align__(16) short As[128][40];
  __shared__ __align__(16) short Bs[128][40];
  int bm = blockIdx.x, bn = blockIdx.y;
  int tid = threadIdx.x;
  int lane = tid & 63, wave = tid >> 6;
  int wm = wave >> 1, wn = wave & 1;
  int row0 = bm * 128, col0 = bn * 128;

  f32x4 acc[4][4] = {};
  int sr = tid >> 1, ss = (tid & 1) * 16;

  for (int k0 = 0; k0 < I_; k0 += 32){
    stage16(A  + (size_t)(row0 + sr) * I_ + k0 + ss, &As[sr][ss]);
    stage16(Wn + (size_t)(col0 + sr) * I_ + k0 + ss, &Bs[sr][ss]);
    __syncthreads();

    int rsel = lane & 15, ko = (lane >> 4) * 8;
    s16x8 af[4], bf[4];
    #pragma unroll
    for (int f = 0; f < 4; ++f){
      af[f] = *(const s16x8*)&As[wm*64 + f*16 + rsel][ko];
      bf[f] = *(const s16x8*)&Bs[wn*64 + f*16 + rsel][ko];
    }
    #pragma unroll
    for (int fm = 0; fm < 4; ++fm)
      #pragma unroll
      for (int fn = 0; fn < 4; ++fn)
        acc[fm][fn] = MFMA16(af[fm], bf[fn], acc[fm][fn]);
    __syncthreads();
  }

  int rbase = (lane >> 4) * 4, cbase = lane & 15;
  #pragma unroll
  for (int fm = 0; fm < 4; ++fm)
    #pragma unroll
    for (int fn = 0; fn < 4; ++fn){
      int gcol = col0 + wn*64 + fn*16 + cbase;
      float b = bias[gcol];
      #pragma unroll
      for (int r = 0; r < 4; ++r){
        int grow = row0 + wm*64 + fm*16 + rbase + r;
        out[(size_t)grow * H_ + gcol] = acc[fm][fn][r] + b;
      }
    }
}

// One recurrence phase (one chain, one step). Uses enclosing-scope:
// t, tid, l, kw, fE, jE, lE, gcol, bias, planes, PLANE, whr, wlr, redT.
#define RUN_PHASE(AOFF, DEPF, FLAGP, HIDROW, GROW, XWV, XWN, VPREV)          \
  {                                                                          \
    if (t > 0){                                                              \
      for (;;){                                                              \
        int f_ = __hip_atomic_load(DEPF, __ATOMIC_RELAXED,                   \
                                   __HIP_MEMORY_SCOPE_AGENT);                \
        if (__all(f_ >= t)) break;                                           \
        __builtin_amdgcn_s_sleep(1);                                         \
      }                                                                      \
      __builtin_amdgcn_sched_barrier(0);                                     \
      const short* aH_ = planes + (size_t)(t & 1) * 2 * PLANE + (AOFF);      \
      const short* aL_ = aH_ + PLANE;                                        \
      s16x8 ah_[4], al_[4];                                                  \
      _Pragma("unroll")                                                      \
      for (int kc = 0; kc < 4; ++kc) ah_[kc] = cload16_l2(aH_ + kc*32);      \
      _Pragma("unroll")                                                      \
      for (int kc = 0; kc < 4; ++kc) al_[kc] = cload16_l2(aL_ + kc*32);      \
      asm volatile("s_waitcnt vmcnt(0)" ::: "memory");                       \
      __builtin_amdgcn_sched_barrier(0);                                     \
      (HIDROW)[(size_t)(t - 1) * H_ + gcol] = (VPREV);                       \
      if (t + 1 < T_) (XWN) = (HIDROW)[(size_t)(t + 1) * H_ + gcol];         \
      f32x4 p0={},p1={},p2={},q0={},q1={},q2={};                             \
      _Pragma("unroll")                                                      \
      for (int kc = 0; kc < 4; ++kc){                                        \
        p0 = MFMA16(ah_[kc], whr[kc*2+0], p0);                               \
        q0 = MFMA16(ah_[kc], whr[kc*2+1], q0);                               \
        p1 = MFMA16(ah_[kc], wlr[kc*2+0], p1);                               \
        q1 = MFMA16(ah_[kc], wlr[kc*2+1], q1);                               \
        p2 = MFMA16(al_[kc], whr[kc*2+0], p2);                               \
        q2 = MFMA16(al_[kc], whr[kc*2+1], q2);                               \
      }                                                                      \
      f32x4 accA_ = (p0 + p1) + p2;                                          \
      f32x4 accB_ = (q0 + q1) + q2;                                          \
      _Pragma("unroll")                                                      \
      for (int j = 0; j < 4; ++j){                                           \
        redT[kw][0][j][l] = accA_[j];                                        \
        redT[kw][1][j][l] = accB_[j];                                        \
      }                                                                      \
    } else {                                                                 \
      (XWN) = (HIDROW)[H_ + gcol];                                           \
    }                                                                        \
    __builtin_amdgcn_sched_barrier(0);                                       \
    asm volatile("s_waitcnt lgkmcnt(0)" ::: "memory");                       \
    __builtin_amdgcn_s_barrier();                                            \
    __builtin_amdgcn_sched_barrier(0);                                       \
    {                                                                        \
      float v_ = 0.f;                                                        \
      if (t > 0){                                                            \
        v_ = redT[0][fE][jE][lE] + redT[1][fE][jE][lE]                       \
           + redT[2][fE][jE][lE] + redT[3][fE][jE][lE]                       \
           + redT[4][fE][jE][lE] + redT[5][fE][jE][lE]                       \
           + redT[6][fE][jE][lE] + redT[7][fE][jE][lE];                      \
      }                                                                      \
      v_ += (XWV) + bias;                                                    \
      v_ = v_ > 0.0f ? v_ : 0.0f;                                            \
      short hh_ = f2bf(v_);                                                  \
      short ll_ = f2bf(v_ - bf2f(hh_));                                      \
      short* oH_ = planes + (size_t)((t + 1) & 1) * 2 * PLANE                \
                 + (size_t)(GROW) * H_ + gcol;                               \
      oH_[0]     = hh_;                                                      \
      oH_[PLANE] = ll_;                                                      \
      (VPREV) = v_;                                                          \
      (XWV) = (XWN);                                                         \
    }                                                                        \
    __syncthreads();                                                         \
    if (tid == 0)                                                            \
      __hip_atomic_store(FLAGP, t + 1, __ATOMIC_RELAXED,                     \
                         __HIP_MEMORY_SCOPE_AGENT);                          \
  }

// ---------------- phase 2: persistent recurrence, dual-chain interleave ----
// 256 wgs, 1/CU (90 KB LDS, DCE-proof) -> 32 wgs per XCD. Each XCD's 32
// batch rows split into two independent 16-row chains A/B; every wg owns a
// 32-col slice of BOTH chains and alternates phaseA(t), phaseB(t). While a
// wg computes chain B, the other wgs' chain-A flags become visible -> the
// next A-poll hits on its first probe (sync latency hidden behind work).
// 8 waves = 8-way K split (128 each). W hi+lo fragments in VGPRs. Transport
// identical to R8/R9: agent flags, sc0 A-loads, plain plane stores, S3+tid0
// publish per phase. Deadlock-free: phase X(t) depends only on X(t-1).
__global__ __launch_bounds__(512, 2) void rnn_persistent(float* __restrict__ hid,
                                                         const float* __restrict__ Wh,
                                                         const float* __restrict__ bh,
                                                         short* __restrict__ planes,
                                                         int* __restrict__ cnt){
  __shared__ __align__(16) float ldsbuf[23040];        // 90 KB (occupancy pin)
  __shared__ int s_role;

  const int PLANE = B_ * H_;                 // 262144 shorts
  int tid = threadIdx.x;
  int l = tid & 63, kw = tid >> 6;           // wave index == K-eighth

  // ---- XCD-local role negotiation (once) ----
  int xcd;
  asm("s_getreg_b32 %0, hwreg(HW_REG_XCC_ID)" : "=s"(xcd));
  if (tid == 0)
    s_role = atomicAdd(cnt + (256 + xcd) * 32, 1);
  __syncthreads();
  int cgp = s_role;                          // 0..31: column-slice owner

  // redT aliased into ldsbuf at an opaque offset (s_role>>8 == 0 at runtime,
  // unprovable at compile time) -> the 90 KB allocation cannot be DCE'd.
  float (*redT)[2][4][65] = (float (*)[2][4][65])(ldsbuf + ((s_role >> 8) * 256));

  // ---- gather W hi+lo fragments into registers (once): 32 cols x K-eighth --
  s16x8 whr[8], wlr[8];
  #pragma unroll
  for (int kc = 0; kc < 4; ++kc){
    #pragma unroll
    for (int f = 0; f < 2; ++f){
      const float* s = Wh + (size_t)(cgp*32 + f*16 + (l & 15)) * H_
                          + kw*128 + kc*32 + ((l >> 4) << 3);
      float4 a0 = *(const float4*)s;
      float4 a1 = *(const float4*)(s + 4);
      float vs[8] = {a0.x, a0.y, a0.z, a0.w, a1.x, a1.y, a1.z, a1.w};
      s16x8 hi8, lo8;
      #pragma unroll
      for (int e = 0; e < 8; ++e){
        short hh = f2bf(vs[e]);
        hi8[e] = hh;
        lo8[e] = f2bf(vs[e] - bf2f(hh));
      }
      whr[kc*2 + f] = hi8;
      wlr[kc*2 + f] = lo8;
    }
  }

  // ---- per-thread constants ----
  int rowA = xcd*32 + (l & 15);                        // chain A A-frag row
  size_t aoffA = (size_t)rowA * H_ + kw*128 + ((l >> 4) << 3);
  size_t aoffB = aoffA + (size_t)16 * H_;              // chain B: +16 rows

  int erow = tid >> 5;                                 // 0..15
  int ecol = tid & 31;                                 // 0..31
  int gcol = cgp*32 + ecol;
  int growA = xcd*32 + erow, growB = growA + 16;
  float bias = bh[gcol];
  float* hidA = hid + (size_t)growA * T_ * H_;
  float* hidB = hid + (size_t)growB * T_ * H_;
  int fE = ecol >> 4, jE = erow & 3;
  int lE = (((erow >> 2) & 3) << 4) | (ecol & 15);

  int* flagA = cnt + (xcd*32 + cgp) * 32;              // per (wg, chain) flags
  int* flagB = flagA + 1;
  const int* depA = cnt + (xcd*32 + kw*4 + (l & 3)) * 32;  // 4 producers/wave
  const int* depB = depA + 1;

  float xwA = hidA[gcol], xwB = hidB[gcol];            // xw(0) both chains
  float xwnA = 0.f, xwnB = 0.f, vPrevA = 0.f, vPrevB = 0.f;

  __syncthreads();                                     // W gather + role settled

  for (int t = 0; t < T_; ++t){
    RUN_PHASE(aoffA, depA, flagA, hidA, growA, xwA, xwnA, vPrevA);
    RUN_PHASE(aoffB, depB, flagB, hidB, growB, xwB, xwnB, vPrevB);
  }

  // final hid rows (step T-1), drained at kernel end
  hidA[(size_t)(T_ - 1) * H_ + gcol] = vPrevA;
  hidB[(size_t)(T_ - 1) * H_ + gcol] = vPrevB;
}

// ---------------- phase 3: out = hidden @ W_o^T + b_o ----------------
__global__ __launch_bounds__(256) void gemm_out(const float* __restrict__ A,
                                                const float* __restrict__ Wo,
                                                const float* __restrict__ bias,
                                                float* __restrict__ out){
  __shared__ __align__(16) short As[128][40];
  __shared__ __align__(16) short Bs[128][40];
  int bm = blockIdx.x;
  int tid = threadIdx.x;
  int lane = tid & 63, wave = tid >> 6;
  int wm = wave >> 1, wn = wave & 1;
  int row0 = bm * 128;

  f32x4 acc[4][4] = {};
  int sr = tid >> 1, ss = (tid & 1) * 16;

  for (int k0 = 0; k0 < H_; k0 += 32){
    stage16(A  + (size_t)(row0 + sr) * H_ + k0 + ss, &As[sr][ss]);
    stage16(Wo + (size_t)sr * H_ + k0 + ss, &Bs[sr][ss]);
    __syncthreads();

    int rsel = lane & 15, ko = (lane >> 4) * 8;
    s16x8 af[4], bf[4];
    #pragma unroll
    for (int f = 0; f < 4; ++f){
      af[f] = *(const s16x8*)&As[wm*64 + f*16 + rsel][ko];
      bf[f] = *(const s16x8*)&Bs[wn*64 + f*16 + rsel][ko];
    }
    #pragma unroll
    for (int fm = 0; fm < 4; ++fm)
      #pragma unroll
      for (int fn = 0; fn < 4; ++fn)
        acc[fm][fn] = MFMA16(af[fm], bf[fn], acc[fm][fn]);
    __syncthreads();
  }

  int rbase = (lane >> 4) * 4, cbase = lane & 15;
  #pragma unroll
  for (int fm = 0; fm < 4; ++fm)
    #pragma unroll
    for (int fn = 0; fn < 4; ++fn){
      int gcol = wn*64 + fn*16 + cbase;
      float b = bias[gcol];
      #pragma unroll
      for (int r = 0; r < 4; ++r){
        int grow = row0 + wm*64 + fm*16 + rbase + r;
        out[(size_t)grow * O_ + gcol] = acc[fm][fn][r] + b;
      }
    }
}

extern "C" void kernel_launch(void* const* d_in, const int* in_sizes, int n_in,
                              void* d_out, int out_size, void* d_ws, size_t ws_size,
                              hipStream_t stream) {
  const float* x    = (const float*)d_in[0];
  const float* W_in = (const float*)d_in[1];
  const float* b_in = (const float*)d_in[2];
  const float* W_h  = (const float*)d_in[3];
  const float* b_h  = (const float*)d_in[4];
  const float* W_o  = (const float*)d_in[5];
  const float* b_o  = (const float*)d_in[6];

  float* out = (float*)d_out;
  float* hid = out + (size_t)BT_ * O_;       // hidden_all region (B,T,H)

  // Scratch inside the (B,T,O) output region (67 MB, dead until phase 3):
  //   planes: 2 slots x (hi+lo) x B_*H_ shorts = 2 MB at offset 0
  //   cnt:    256 flag lines + 8 role counters (128 B stride) at 4 MB
  short* planes = (short*)d_out;
  int*   cnt    = (int*)(out + (1 << 20));

  init_cnt<<<1, 1024, 0, stream>>>(cnt);

  gemm_xw<<<dim3(BT_/128, H_/128), 256, 0, stream>>>(x, W_in, b_in, hid);

  {
    float* hid_p = hid;
    const float* Wh_p = W_h;
    const float* bh_p = b_h;
    short* planes_p = planes;
    int* cnt_p = cnt;
    void* args[] = { &hid_p, &Wh_p, &bh_p, &planes_p, &cnt_p };
    hipLaunchCooperativeKernel((const void*)rnn_persistent,
                               dim3(256), dim3(512), args, 0, stream);
  }

  gemm_out<<<dim3(BT_/128), 256, 0, stream>>>(hid, W_o, b_o, out);
}